// Round 23
// baseline (117.864 us; speedup 1.0000x reference)
//
#include <hip/hip_runtime.h>
#include <hip/hip_bf16.h>

#define SEQ  256
#define DIM  20
#define NCLS 5
#define ALPHA 2.8853900817779268f   // 2*log2(e), folded into recurrent weights

typedef short  bf16x8 __attribute__((ext_vector_type(8)));
typedef float  f32x4  __attribute__((ext_vector_type(4)));
typedef float  v2f    __attribute__((ext_vector_type(2)));

// tanh from PRE-SCALED input (xs = 2*log2e*pre): 1 - 2/(exp2(xs)+1).
// Paired reciprocal: one v_rcp serves both lanes (d>=1, no overflow).
__device__ __forceinline__ v2f fast_tanh2_s(v2f xs) {
    v2f e;
    e.x = __builtin_amdgcn_exp2f(xs.x);
    e.y = __builtin_amdgcn_exp2f(xs.y);
    v2f d = e + 1.0f;
    const float r = __builtin_amdgcn_rcpf(d.x * d.y);
    v2f inv;
    inv.x = d.y * r;
    inv.y = d.x * r;
    return __builtin_elementwise_fma((v2f)(-2.0f), inv, (v2f)(1.0f));
}

__device__ __forceinline__ int cvt_pk_bf16(float lo, float hi) {
    int r;
    asm("v_cvt_pk_bf16_f32 %0, %1, %2" : "=v"(r) : "v"(lo), "v"(hi));
    return r;
}

// v_permlane32_swap_b32 (S1 semantics, established r8/r9):
//   a' = {a_low, b_low}; b' = {a_high, b_high}
__device__ __forceinline__ void pl32swap(int &a, int &b) {
    asm("v_permlane32_swap_b32 %0, %1" : "+v"(a), "+v"(b));
}

// Recurrent k-permutation (A-column kappa holds unit perm(kappa)):
// [0-3]->u0-3, [4-7]->u8-11, [8-11]->u4-7, [12-15]->u12-15, [16-19]->u16-19.
__device__ __forceinline__ int permk(int k) {
    return (k >= 4 && k < 8) ? k + 4 : (k >= 8 && k < 12) ? k - 4 : k;
}

union I4B { int i[4]; bf16x8 f; };

// ---- per-tile pipeline state (suffix S = P or Q) ---------------------------
#define TILE_PROLOG(S, XP)                                                     \
    I4B Bh##S; Bh##S.i[0] = Bh##S.i[1] = Bh##S.i[2] = Bh##S.i[3] = 0;          \
    f32x4 aePre0##S, aePre1##S;                                                \
    {                                                                          \
        const int tk0 = (XP)[0];                                               \
        const f32x4 lo = *(const f32x4*)(emb + (size_t)tk0 * DIM + eoff0);     \
        const f32x4 hi = *(const f32x4*)(emb + (size_t)tk0 * DIM + eoff1);     \
        const bool nz = (tk0 != 0);        /* padding_idx = 0 */               \
        I4B Be;                                                                \
        Be.i[0] = nz ? cvt_pk_bf16(lo[0], lo[1]) : 0;                          \
        Be.i[1] = nz ? cvt_pk_bf16(lo[2], lo[3]) : 0;                          \
        Be.i[2] = nz ? cvt_pk_bf16(hi[0], hi[1]) : 0;                          \
        Be.i[3] = nz ? cvt_pk_bf16(hi[2], hi[3]) : 0;                          \
        aePre0##S = __builtin_amdgcn_mfma_f32_16x16x32_bf16(A0e, Be.f, zf, 0, 0, 0); \
        aePre1##S = __builtin_amdgcn_mfma_f32_16x16x32_bf16(A1e, Be.f, zf, 0, 0, 0); \
    }                                                                          \
    const int tk1##S = (XP)[1], tk2##S = (XP)[2], tk3##S = (XP)[3], tk4##S = (XP)[4]; \
    f32x4 loA##S, hiA##S, loB##S, hiB##S, loC##S, hiC##S, loD##S, hiD##S;      \
    bool nzA##S, nzB##S, nzC##S, nzD##S;                                       \
    loA##S = *(const f32x4*)(emb + (size_t)tk1##S * DIM + eoff0);              \
    hiA##S = *(const f32x4*)(emb + (size_t)tk1##S * DIM + eoff1);              \
    nzA##S = (tk1##S != 0);                                                    \
    loB##S = *(const f32x4*)(emb + (size_t)tk2##S * DIM + eoff0);              \
    hiB##S = *(const f32x4*)(emb + (size_t)tk2##S * DIM + eoff1);              \
    nzB##S = (tk2##S != 0);                                                    \
    loC##S = *(const f32x4*)(emb + (size_t)tk3##S * DIM + eoff0);              \
    hiC##S = *(const f32x4*)(emb + (size_t)tk3##S * DIM + eoff1);              \
    nzC##S = (tk3##S != 0);                                                    \
    loD##S = *(const f32x4*)(emb + (size_t)tk4##S * DIM + eoff0);              \
    hiD##S = *(const f32x4*)(emb + (size_t)tk4##S * DIM + eoff1);              \
    nzD##S = (tk4##S != 0);                                                    \
    int tokG0##S = (XP)[5], tokG1##S = (XP)[6], tokG2##S = (XP)[7], tokG3##S = (XP)[8];

// ---- step phases (interleaved P/Q so each tile's latency hides under the
// other tile's independent work; ordering r20-proven) ------------------------
#define PH_GATHER(S, TIDX)                                                     \
    const f32x4 loN##S = *(const f32x4*)(emb + (size_t)tokG0##S * DIM + eoff0);\
    const f32x4 hiN##S = *(const f32x4*)(emb + (size_t)tokG0##S * DIM + eoff1);\
    const bool  nzN##S = (tokG0##S != 0);                                      \
    const int tokNew##S = xp##S[(TIDX)];

#define PH_HMFMA(S)                                                            \
    const f32x4 acc1##S = __builtin_amdgcn_mfma_f32_16x16x32_bf16(A1h, Bh##S.f, aePre1##S, 0, 0, 0); \
    const f32x4 acc0##S = __builtin_amdgcn_mfma_f32_16x16x32_bf16(A0h, Bh##S.f, aePre0##S, 0, 0, 0);

#define PH_EPATH(S)                                                            \
    {                                                                          \
        I4B Be;                                                                \
        Be.i[0] = nzA##S ? cvt_pk_bf16(loA##S[0], loA##S[1]) : 0;              \
        Be.i[1] = nzA##S ? cvt_pk_bf16(loA##S[2], loA##S[3]) : 0;              \
        Be.i[2] = nzA##S ? cvt_pk_bf16(hiA##S[0], hiA##S[1]) : 0;              \
        Be.i[3] = nzA##S ? cvt_pk_bf16(hiA##S[2], hiA##S[3]) : 0;              \
        aePre0##S = __builtin_amdgcn_mfma_f32_16x16x32_bf16(A0e, Be.f, zf, 0, 0, 0); \
        aePre1##S = __builtin_amdgcn_mfma_f32_16x16x32_bf16(A1e, Be.f, zf, 0, 0, 0); \
    }

#define PH_TANH(S)                                                             \
    {                                                                          \
        const v2f p2 = fast_tanh2_s((v2f){acc1##S[0], acc1##S[1]});            \
        const v2f p3 = fast_tanh2_s((v2f){acc1##S[2], acc1##S[3]});            \
        int tp0 = cvt_pk_bf16(p2.x, p2.y);                                     \
        int tp1 = cvt_pk_bf16(p3.x, p3.y);                                     \
        const v2f p0 = fast_tanh2_s((v2f){acc0##S[0], acc0##S[1]});            \
        const v2f p1 = fast_tanh2_s((v2f){acc0##S[2], acc0##S[3]});            \
        int w0 = cvt_pk_bf16(p0.x, p0.y);                                      \
        int w1 = cvt_pk_bf16(p1.x, p1.y);                                      \
        pl32swap(w0, tp0);   /* w'={w_lo,t_lo}; t'={w_hi,t_hi} */              \
        pl32swap(w1, tp1);                                                     \
        Bh##S.i[0] = w0; Bh##S.i[1] = w1; Bh##S.i[2] = tp0; Bh##S.i[3] = tp1;  \
    }

#define PH_ROT(S)                                                              \
    loA##S = loB##S; hiA##S = hiB##S; nzA##S = nzB##S;                         \
    loB##S = loC##S; hiB##S = hiC##S; nzB##S = nzC##S;                         \
    loC##S = loD##S; hiC##S = hiD##S; nzC##S = nzD##S;                         \
    loD##S = loN##S; hiD##S = hiN##S; nzD##S = nzN##S;                         \
    tokG0##S = tokG1##S; tokG1##S = tokG2##S; tokG2##S = tokG3##S; tokG3##S = tokNew##S;

// one step for BOTH tiles, phases interleaved
#define STEP2(TIDX)                                                            \
    {                                                                          \
        PH_GATHER(P, TIDX)                                                     \
        PH_GATHER(Q, TIDX)                                                     \
        PH_HMFMA(P)                                                            \
        PH_HMFMA(Q)                                                            \
        PH_EPATH(P)                                                            \
        PH_EPATH(Q)                                                            \
        PH_TANH(P)                                                             \
        PH_TANH(Q)                                                             \
        PH_ROT(P)                                                              \
        PH_ROT(Q)                                                              \
    }

// One wave = TWO 16-row tiles (P: rows w*32.., Q: rows w*32+16..), phases
// interleaved so each tile's MFMA/tanh chain latency is hidden under the
// other tile's independent issue. Shared A-fragments; no barriers, no DS.
// 512 waves, 1 wave/SIMD (pinned via waves_per_eu(1,1), r17-proven).
__global__ __launch_bounds__(64)
__attribute__((amdgpu_waves_per_eu(1, 1)))
void rnn_mfma2(const int* __restrict__ x,
               const float* __restrict__ emb,
               const float* __restrict__ W_ih,
               const float* __restrict__ W_hh,
               const float* __restrict__ W_cls,
               const float* __restrict__ b_cls,
               float* __restrict__ out, int B)
{
    const int wave = (int)blockIdx.x;     // one wave per 64-thread block
    const int lane = (int)(threadIdx.x & 63);
    const int c = lane & 15;              // batch column within tile
    const int q = lane >> 4;              // quadrant
    const int row0P = wave * 32;
    const int row0Q = row0P + 16;
    if (row0P >= B) return;

    // ---- A fragments (shared by both tiles): A[row=c][k=8q+j], zero padded.
    auto loadA = [&](const float* M, int U0, int ROWS, bool pk, float scale) {
        bf16x8 f;
        const int uu = U0 + c;
        const int ur = uu < ROWS ? uu : 0;
#pragma unroll
        for (int j = 0; j < 8; ++j) {
            const int kk = 8 * q + j;
            const int kp = pk ? permk(kk) : kk;
            const int kr = kp < DIM ? kp : 0;
            float v = M[ur * DIM + kr] * scale;
            v = (uu < ROWS && kk < DIM) ? v : 0.0f;
            __hip_bfloat16 hb = __float2bfloat16(v);
            f[j] = *reinterpret_cast<short*>(&hb);
        }
        return f;
    };
    const bf16x8 A0h = loadA(W_hh,  0, DIM,  true,  ALPHA);  // units 0-15
    const bf16x8 A0e = loadA(W_ih,  0, DIM,  false, ALPHA);
    const bf16x8 A1h = loadA(W_hh, 16, DIM,  true,  ALPHA);  // units 16-19
    const bf16x8 A1e = loadA(W_ih, 16, DIM,  false, ALPHA);
    const bf16x8 Acl = loadA(W_cls, 0, NCLS, true,  1.0f);   // classes 0-4

    float bias[4];
#pragma unroll
    for (int j = 0; j < 4; ++j) {
        const int idx = 4 * q + j;
        bias[j] = (idx < NCLS) ? b_cls[idx] : 0.0f;
    }

    const int eoff0 = (q == 0) ? 0 : (q == 1) ? 8 : 16;   // e element offsets,
    const int eoff1 = (q == 0) ? 4 : (q == 1) ? 12 : 16;  // clamped in-bounds

    const int* xpP = x + (size_t)(row0P + c) * SEQ;
    const int* xpQ = x + (size_t)(row0Q + c) * SEQ;
    const f32x4 zf = {0.0f, 0.0f, 0.0f, 0.0f};

    // ---- prologues ---------------------------------------------------------
    TILE_PROLOG(P, xpP)
    TILE_PROLOG(Q, xpQ)

    // ---- main loop: no clamp while s+9 <= 255; 240 is 4-aligned ------------
#pragma unroll 4
    for (int s = 0; s < 240; ++s) {
        STEP2(s + 9)
    }
    // ---- tail: 16 steps with clamped token index ---------------------------
#pragma unroll 4
    for (int s = 240; s < SEQ; ++s) {
        STEP2((s + 9 < SEQ) ? (s + 9) : (SEQ - 1))
    }

    // ---- classifiers (one MFMA per tile; k-cols >= 20 are zero) ------------
    const f32x4 yP = __builtin_amdgcn_mfma_f32_16x16x32_bf16(Acl, BhP.f, zf, 0, 0, 0);
    const f32x4 yQ = __builtin_amdgcn_mfma_f32_16x16x32_bf16(Acl, BhQ.f, zf, 0, 0, 0);
    {
        float* orow = out + (size_t)(row0P + c) * NCLS;
        if (q == 0) {
            orow[0] = yP[0] + bias[0];
            orow[1] = yP[1] + bias[1];
            orow[2] = yP[2] + bias[2];
            orow[3] = yP[3] + bias[3];
        } else if (q == 1) {
            orow[4] = yP[0] + bias[0];
        }
    }
    {
        float* orow = out + (size_t)(row0Q + c) * NCLS;
        if (q == 0) {
            orow[0] = yQ[0] + bias[0];
            orow[1] = yQ[1] + bias[1];
            orow[2] = yQ[2] + bias[2];
            orow[3] = yQ[3] + bias[3];
        } else if (q == 1) {
            orow[4] = yQ[0] + bias[0];
        }
    }
}

extern "C" void kernel_launch(void* const* d_in, const int* in_sizes, int n_in,
                              void* d_out, int out_size, void* d_ws, size_t ws_size,
                              hipStream_t stream) {
    const int*   x     = (const int*)d_in[0];
    const float* emb   = (const float*)d_in[1];
    const float* W_ih  = (const float*)d_in[2];
    const float* W_hh  = (const float*)d_in[3];
    const float* W_cls = (const float*)d_in[4];
    const float* b_cls = (const float*)d_in[5];
    float* out = (float*)d_out;

    const int B = in_sizes[0] / SEQ;            // 16384
    const int waves = (B + 31) / 32;             // 512 waves, 2 tiles each
    rnn_mfma2<<<waves, 64, 0, stream>>>(x, emb, W_ih, W_hh, W_cls, b_cls, out, B);
}

// Round 24
// 68.523 us; speedup vs baseline: 1.7201x; 1.7201x over previous
//
#include <hip/hip_runtime.h>
#include <hip/hip_bf16.h>

#define SEQ  256
#define DIM  20
#define NCLS 5
#define ALPHA 2.8853900817779268f   // 2*log2(e): folded into recurrent weights

typedef short  bf16x8 __attribute__((ext_vector_type(8)));
typedef float  f32x4  __attribute__((ext_vector_type(4)));
typedef float  v2f    __attribute__((ext_vector_type(2)));

// tanh from PRE-SCALED input (xs = 2*log2e * pre): 1 - 2/(exp2(xs)+1).
// Paired reciprocal: one v_rcp serves both lanes of the pair (product of the
// two denominators; d >= 1 so prod in [1, ~1e9] -- no overflow, rel err ~1e-7).
__device__ __forceinline__ v2f fast_tanh2_s(v2f xs) {
    v2f e;
    e.x = __builtin_amdgcn_exp2f(xs.x);
    e.y = __builtin_amdgcn_exp2f(xs.y);
    v2f d = e + 1.0f;                     // v_pk_add_f32
    const float r = __builtin_amdgcn_rcpf(d.x * d.y);
    v2f inv;
    inv.x = d.y * r;
    inv.y = d.x * r;
    return __builtin_elementwise_fma((v2f)(-2.0f), inv, (v2f)(1.0f));
}

__device__ __forceinline__ int cvt_pk_bf16(float lo, float hi) {
    int r;
    asm("v_cvt_pk_bf16_f32 %0, %1, %2" : "=v"(r) : "v"(lo), "v"(hi));
    return r;
}

// v_permlane32_swap_b32 a, b  (S1 semantics, established by r8/r9 A-B result):
//   a' : lanes 0-31 = a(0-31),  lanes 32-63 = b(0-31)
//   b' : lanes 0-31 = a(32-63), lanes 32-63 = b(32-63)
__device__ __forceinline__ void pl32swap(int &a, int &b) {
    asm("v_permlane32_swap_b32 %0, %1" : "+v"(a), "+v"(b));
}

// Recurrent-contraction column permutation (A-column kappa holds unit
// perm(kappa)): [0-3]->u0-3, [4-7]->u8-11, [8-11]->u4-7, [12-15]->u12-15,
// [16-19]->u16-19. Whole h-exchange = 2 permlane32_swap, zero DS.
__device__ __forceinline__ int permk(int k) {
    return (k >= 4 && k < 8) ? k + 4 : (k >= 8 && k < 12) ? k - 4 : k;
}

union I4B { int i[4]; bf16x8 f; };

// One RNN step. Ordering tuned for the in-order single-wave pipeline (r20):
//   1. gather + token issue (VMEM, covered 4 iterations ahead)
//   2. h-MFMA tile1 then tile0 (acc1 result arrives first)
//   3. e-path (independent) fills the MFMA latency shadow
//   4. tanh tile1 -> pack t's (acc0 latency hides under tile1 trans work)
//   5. tanh tile0 -> pack w's -> 2 permlane swaps -> Bh
// Weights pre-scaled by ALPHA: acc is already in exp2 units (no pk_mul).
#define STEP(TIDX)                                                            \
    {                                                                          \
        const f32x4 loN = *(const f32x4*)(emb + (size_t)tokG0 * DIM + eoff0);  \
        const f32x4 hiN = *(const f32x4*)(emb + (size_t)tokG0 * DIM + eoff1);  \
        const bool  nzN = (tokG0 != 0);                                        \
        const int tokNew = xp[(TIDX)];                                         \
        const f32x4 acc1 = __builtin_amdgcn_mfma_f32_16x16x32_bf16(A1h, Bh.f, aePre1, 0, 0, 0); \
        const f32x4 acc0 = __builtin_amdgcn_mfma_f32_16x16x32_bf16(A0h, Bh.f, aePre0, 0, 0, 0); \
        I4B Be;                                                                \
        Be.i[0] = nzA ? cvt_pk_bf16(loA[0], loA[1]) : 0;                       \
        Be.i[1] = nzA ? cvt_pk_bf16(loA[2], loA[3]) : 0;                       \
        Be.i[2] = nzA ? cvt_pk_bf16(hiA[0], hiA[1]) : 0;                       \
        Be.i[3] = nzA ? cvt_pk_bf16(hiA[2], hiA[3]) : 0;                       \
        aePre0 = __builtin_amdgcn_mfma_f32_16x16x32_bf16(A0e, Be.f, zf, 0, 0, 0); \
        aePre1 = __builtin_amdgcn_mfma_f32_16x16x32_bf16(A1e, Be.f, zf, 0, 0, 0); \
        const v2f p2 = fast_tanh2_s((v2f){acc1[0], acc1[1]});                  \
        const v2f p3 = fast_tanh2_s((v2f){acc1[2], acc1[3]});                  \
        int tp0 = cvt_pk_bf16(p2.x, p2.y);                                     \
        int tp1 = cvt_pk_bf16(p3.x, p3.y);                                     \
        const v2f p0 = fast_tanh2_s((v2f){acc0[0], acc0[1]});                  \
        const v2f p1 = fast_tanh2_s((v2f){acc0[2], acc0[3]});                  \
        int w0 = cvt_pk_bf16(p0.x, p0.y);                                      \
        int w1 = cvt_pk_bf16(p1.x, p1.y);                                      \
        pl32swap(w0, tp0);   /* w'={w_lo,t_lo}; t'={w_hi,t_hi} */              \
        pl32swap(w1, tp1);                                                     \
        Bh.i[0] = w0; Bh.i[1] = w1; Bh.i[2] = tp0; Bh.i[3] = tp1;              \
        loA = loB; hiA = hiB; nzA = nzB;                                       \
        loB = loC; hiB = hiC; nzB = nzC;                                       \
        loC = loD; hiC = hiD; nzC = nzD;                                       \
        loD = loN; hiD = hiN; nzD = nzN;                                       \
        tokG0 = tokG1; tokG1 = tokG2; tokG2 = tokG3; tokG3 = tokNew;           \
    }

// One wave = 16 batch rows; plain loads; scheduler occupancy pinned to
// 1 wave/EU (r17-proven: keeps pipeline registers live, VGPR 48->132).
__global__ __launch_bounds__(256)
__attribute__((amdgpu_waves_per_eu(1, 1)))
void rnn_mfma(const int* __restrict__ x,
              const float* __restrict__ emb,
              const float* __restrict__ W_ih,
              const float* __restrict__ W_hh,
              const float* __restrict__ W_cls,
              const float* __restrict__ b_cls,
              float* __restrict__ out, int B)
{
    const int gtid = blockIdx.x * blockDim.x + threadIdx.x;
    const int wave = gtid >> 6;
    const int lane = (int)(threadIdx.x & 63);
    const int c = lane & 15;      // batch column of the tile
    const int q = lane >> 4;      // quadrant
    const int row0 = wave * 16;
    if (row0 >= B) return;

    // ---- A fragments: lane holds A[row=c][k=8q+j], zero outside bounds.
    // scale: recurrent matrices absorb ALPHA so MFMA output is exp2-ready.
    auto loadA = [&](const float* M, int U0, int ROWS, bool pk, float scale) {
        bf16x8 f;
        const int uu = U0 + c;
        const int ur = uu < ROWS ? uu : 0;
#pragma unroll
        for (int j = 0; j < 8; ++j) {
            const int kk = 8 * q + j;
            const int kp = pk ? permk(kk) : kk;
            const int kr = kp < DIM ? kp : 0;
            float v = M[ur * DIM + kr] * scale;
            v = (uu < ROWS && kk < DIM) ? v : 0.0f;
            __hip_bfloat16 hb = __float2bfloat16(v);
            f[j] = *reinterpret_cast<short*>(&hb);
        }
        return f;
    };
    const bf16x8 A0h = loadA(W_hh,  0, DIM,  true,  ALPHA);  // units 0-15,  W_hh
    const bf16x8 A0e = loadA(W_ih,  0, DIM,  false, ALPHA);  // units 0-15,  W_ih
    const bf16x8 A1h = loadA(W_hh, 16, DIM,  true,  ALPHA);  // units 16-19
    const bf16x8 A1e = loadA(W_ih, 16, DIM,  false, ALPHA);
    const bf16x8 Acl = loadA(W_cls, 0, NCLS, true,  1.0f);   // classes 0-4

    float bias[4];
#pragma unroll
    for (int j = 0; j < 4; ++j) {
        const int idx = 4 * q + j;
        bias[j] = (idx < NCLS) ? b_cls[idx] : 0.0f;
    }

    const int eoff0 = (q == 0) ? 0 : (q == 1) ? 8 : 16;   // e element offsets,
    const int eoff1 = (q == 0) ? 4 : (q == 1) ? 12 : 16;  // clamped in-bounds

    const int* xp = x + (size_t)(row0 + c) * SEQ;
    const f32x4 zf = {0.0f, 0.0f, 0.0f, 0.0f};

    // ---- prologue ----------------------------------------------------------
    I4B Bh; Bh.i[0] = Bh.i[1] = Bh.i[2] = Bh.i[3] = 0;
    const int tk0 = xp[0];
    const int tk1 = xp[1];
    const int tk2 = xp[2];
    const int tk3 = xp[3];
    const int tk4 = xp[4];
    f32x4 aePre0, aePre1;
    {   // e(0) -> aePre for step 0
        const f32x4 lo = *(const f32x4*)(emb + (size_t)tk0 * DIM + eoff0);
        const f32x4 hi = *(const f32x4*)(emb + (size_t)tk0 * DIM + eoff1);
        const bool nz = (tk0 != 0);    // padding_idx = 0
        I4B Be;
        Be.i[0] = nz ? cvt_pk_bf16(lo[0], lo[1]) : 0;
        Be.i[1] = nz ? cvt_pk_bf16(lo[2], lo[3]) : 0;
        Be.i[2] = nz ? cvt_pk_bf16(hi[0], hi[1]) : 0;
        Be.i[3] = nz ? cvt_pk_bf16(hi[2], hi[3]) : 0;
        aePre0 = __builtin_amdgcn_mfma_f32_16x16x32_bf16(A0e, Be.f, zf, 0, 0, 0);
        aePre1 = __builtin_amdgcn_mfma_f32_16x16x32_bf16(A1e, Be.f, zf, 0, 0, 0);
    }

    // stages A..D = e(1)..e(4); tokens x[5..8] in flight
    f32x4 loA, hiA, loB, hiB, loC, hiC, loD, hiD;
    bool nzA, nzB, nzC, nzD;
    loA = *(const f32x4*)(emb + (size_t)tk1 * DIM + eoff0);
    hiA = *(const f32x4*)(emb + (size_t)tk1 * DIM + eoff1);
    nzA = (tk1 != 0);
    loB = *(const f32x4*)(emb + (size_t)tk2 * DIM + eoff0);
    hiB = *(const f32x4*)(emb + (size_t)tk2 * DIM + eoff1);
    nzB = (tk2 != 0);
    loC = *(const f32x4*)(emb + (size_t)tk3 * DIM + eoff0);
    hiC = *(const f32x4*)(emb + (size_t)tk3 * DIM + eoff1);
    nzC = (tk3 != 0);
    loD = *(const f32x4*)(emb + (size_t)tk4 * DIM + eoff0);
    hiD = *(const f32x4*)(emb + (size_t)tk4 * DIM + eoff1);
    nzD = (tk4 != 0);
    int tokG0 = xp[5];
    int tokG1 = xp[6];
    int tokG2 = xp[7];
    int tokG3 = xp[8];

    // ---- main loop: no clamp needed while s+9 <= 255; 240 is 8-aligned -----
#pragma unroll 8
    for (int s = 0; s < 240; ++s) {
        STEP(s + 9)
    }
    // ---- tail: 16 steps with clamped token index ---------------------------
#pragma unroll 4
    for (int s = 240; s < SEQ; ++s) {
        STEP((s + 9 < SEQ) ? (s + 9) : (SEQ - 1))
    }

    // ---- classifier: one MFMA (classes in rows 0-4; k-cols >= 20 are zero)
    const f32x4 y = __builtin_amdgcn_mfma_f32_16x16x32_bf16(Acl, Bh.f, zf, 0, 0, 0);
    float* orow = out + (size_t)(row0 + c) * NCLS;
    if (q == 0) {          // rows 0-3 = classes 0-3 for batch row c
        orow[0] = y[0] + bias[0];
        orow[1] = y[1] + bias[1];
        orow[2] = y[2] + bias[2];
        orow[3] = y[3] + bias[3];
    } else if (q == 1) {   // row 4 = class 4
        orow[4] = y[0] + bias[0];
    }
}

extern "C" void kernel_launch(void* const* d_in, const int* in_sizes, int n_in,
                              void* d_out, int out_size, void* d_ws, size_t ws_size,
                              hipStream_t stream) {
    const int*   x     = (const int*)d_in[0];
    const float* emb   = (const float*)d_in[1];
    const float* W_ih  = (const float*)d_in[2];
    const float* W_hh  = (const float*)d_in[3];
    const float* W_cls = (const float*)d_in[4];
    const float* b_cls = (const float*)d_in[5];
    float* out = (float*)d_out;

    const int B = in_sizes[0] / SEQ;            // 16384
    const int threads = B * 4;                   // 64 lanes per 16 rows
    const int block = 256;
    const int grid = (threads + block - 1) / block;   // 1024 waves total
    rnn_mfma<<<grid, block, 0, stream>>>(x, emb, W_ih, W_hh, W_cls, b_cls, out, B);
}